// Round 3
// baseline (444.236 us; speedup 1.0000x reference)
//
#include <hip/hip_runtime.h>
#include <math.h>

#define TT 2048
#define HH 1024
#define NE 40
#define ER 32
#define II 512
#define TOPK 4
#define RSCALE 2.5f
#define MAXW 64    // max m-tiles of 256: 8192/256 + 32

typedef __bf16 bf16x8 __attribute__((ext_vector_type(8)));
typedef float f32x4 __attribute__((ext_vector_type(4)));

// async global->LDS, 16B per lane; LDS dest is wave-uniform base + lane*16
__device__ __forceinline__ void glds16(const void* g, void* l) {
  __builtin_amdgcn_global_load_lds(
      (const __attribute__((address_space(1))) unsigned int*)g,
      (__attribute__((address_space(3))) unsigned int*)l, 16, 0, 0);
}

__device__ __forceinline__ void st_bf4(void* dst, float4 v) {
  union { __bf16 h[4]; uint2 u; } pk;
  pk.h[0] = (__bf16)v.x; pk.h[1] = (__bf16)v.y;
  pk.h[2] = (__bf16)v.z; pk.h[3] = (__bf16)v.w;
  *(uint2*)dst = pk.u;
}

// ---------------- K0: zero the global expert counters -----------------------
__global__ __launch_bounds__(64) void k_zero(int* __restrict__ cnt) {
  if (threadIdx.x < 32) cnt[threadIdx.x] = 0;
}

// ---------------- K1: fused router + global expert counting -----------------
// One wave per token. fp32 logits REQUIRED (bf16 error ~2.6e-3 flips top-4).
// Also: out = hidden * zero_total, hid_bf = bf16(hidden); lane0 atomically
// counts routed assignments into cnt[] (parallel replacement for the old
// single-block count phase).
__global__ __launch_bounds__(256) void k_router(const float* __restrict__ hidden,
                                                const float* __restrict__ rw,
                                                const float* __restrict__ bias,
                                                float* __restrict__ out,
                                                int* __restrict__ tok4_id,
                                                float* __restrict__ tok4_w,
                                                __bf16* __restrict__ hid_bf,
                                                int* __restrict__ cnt) {
  int lane = threadIdx.x & 63;
  int t = blockIdx.x * 4 + (threadIdx.x >> 6);
  const float* hrow = hidden + (size_t)t * HH;
  float4 hv[4];
  #pragma unroll
  for (int c = 0; c < 4; c++) hv[c] = *(const float4*)(hrow + c * 256 + lane * 4);

  float mylg = -INFINITY;
  for (int e = 0; e < NE; e++) {
    const float* wrow = rw + (size_t)e * HH;
    float p = 0.f;
    #pragma unroll
    for (int c = 0; c < 4; c++) {
      float4 w4 = *(const float4*)(wrow + c * 256 + lane * 4);
      p += hv[c].x * w4.x + hv[c].y * w4.y + hv[c].z * w4.z + hv[c].w * w4.w;
    }
    #pragma unroll
    for (int off = 32; off; off >>= 1) p += __shfl_xor(p, off);
    if (lane == e) mylg = p;
  }
  float m = mylg;
  #pragma unroll
  for (int off = 32; off; off >>= 1) m = fmaxf(m, __shfl_xor(m, off));
  float p = (lane < NE) ? expf(mylg - m) : 0.f;
  float s = p;
  #pragma unroll
  for (int off = 32; off; off >>= 1) s += __shfl_xor(s, off);
  float score = p / s;
  float v = (lane < NE) ? score + bias[lane] : -INFINITY;
  int ids[TOPK]; float wv[TOPK];
  #pragma unroll
  for (int k = 0; k < TOPK; k++) {
    float mv = v;
    int mi = (lane < NE) ? lane : 63;
    #pragma unroll
    for (int off = 32; off; off >>= 1) {      // argmax, tie -> lower idx
      float ov = __shfl_xor(mv, off);
      int oi = __shfl_xor(mi, off);
      if (ov > mv || (ov == mv && oi < mi)) { mv = ov; mi = oi; }
    }
    ids[k] = mi;
    wv[k] = RSCALE * __shfl(score, mi);       // weight from UNBIASED score
    if (lane == mi) v = -INFINITY;
  }
  float zt = 0.f;
  #pragma unroll
  for (int k = 0; k < TOPK; k++) if (ids[k] >= ER) zt += wv[k];
  if (lane == 0) {
    #pragma unroll
    for (int k = 0; k < TOPK; k++) {
      tok4_id[t * TOPK + k] = ids[k];
      tok4_w[t * TOPK + k] = wv[k];
      if (ids[k] < ER) atomicAdd(&cnt[ids[k]], 1);
    }
  }
  #pragma unroll
  for (int c = 0; c < 4; c++) {
    int j = c * 256 + lane * 4;
    float4 h4 = hv[c];
    *(float4*)(out + (size_t)t * HH + j) =
        make_float4(h4.x * zt, h4.y * zt, h4.z * zt, h4.w * zt);
    union { __bf16 h[4]; uint2 u; } pk;
    pk.h[0] = (__bf16)h4.x; pk.h[1] = (__bf16)h4.y;
    pk.h[2] = (__bf16)h4.z; pk.h[3] = (__bf16)h4.w;
    *(uint2*)(hid_bf + (size_t)t * HH + j) = pk.u;
  }
}

// ---------------- K2a: tiny scan over 32 counters + worklist ----------------
__global__ __launch_bounds__(64) void k_scan(const int* __restrict__ cnt,
                                             int* __restrict__ offs,
                                             int* __restrict__ wl_e,
                                             int* __restrict__ wl_m0,
                                             int* __restrict__ nwork,
                                             int* __restrict__ gcur) {
  int lane = threadIdx.x;
  int c = (lane < ER) ? cnt[lane] : 0;
  int ts = (c + 255) >> 8;                  // 256-row tiles
  int ps = c, pt = ts;
  #pragma unroll
  for (int off = 1; off < 32; off <<= 1) {
    int v1 = __shfl_up(ps, off);
    int v2 = __shfl_up(pt, off);
    if (lane >= off) { ps += v1; pt += v2; }
  }
  if (lane < ER) {
    int o = ps - c;
    offs[lane] = o; gcur[lane] = o;
    int tb = pt - ts;
    for (int i = 0; i < ts; i++) { wl_e[tb + i] = lane; wl_m0[tb + i] = i * 256; }
  }
  if (lane == 31) *nwork = pt;
}

// ---------------- K2b: parallel scatter (32 blocks, global-atomic slots) ----
__global__ __launch_bounds__(256) void k_scatter(const int* __restrict__ tok4_id,
                                                 const float* __restrict__ tok4_w,
                                                 int* __restrict__ gcur,
                                                 int* __restrict__ pair_tok,
                                                 float* __restrict__ pair_w) {
  int idx = blockIdx.x * 256 + threadIdx.x;
  int id = tok4_id[idx];
  if (id < ER) {
    int pos = atomicAdd(&gcur[id], 1);
    pair_tok[pos] = idx >> 2;
    pair_w[pos] = tok4_w[idx];
  }
}

// ---------------- K3: h = silu(X@Wg^T)*(X@Wu^T), M=256 x N=16 tile ----------
// 2-phase async pipeline: global_load_lds stages A(t+1) into buf^1 while
// MFMAs consume buf (loads fly under compute; __syncthreads' vmcnt(0) drain
// only pays the residual). B (fp32->bf16) reg-staged, ds_written post-MFMA.
// A swizzle via pre-swizzled GLOBAL source (glds dest must stay linear):
// lane (lr,lc) fetches k-chunk lc^lr; reader XORs chunk with row&7.
__global__ __launch_bounds__(256) void k_w13(const __bf16* __restrict__ hid_bf,
                                             const float* __restrict__ w13,
                                             const int* __restrict__ cnt,
                                             const int* __restrict__ offs,
                                             const int* __restrict__ pair_tok,
                                             const int* __restrict__ wl_e,
                                             const int* __restrict__ wl_m0,
                                             const int* __restrict__ nwork,
                                             __bf16* __restrict__ h_buf) {
  int bx = blockIdx.x;
  if (bx >= *nwork) return;
  int e = wl_e[bx], m0w = wl_m0[bx];
  int M = cnt[e] - m0w; if (M > 256) M = 256;
  int base = offs[e] + m0w;
  int n0 = blockIdx.y * 16;

  __shared__ __bf16 As[2][256][64];   // 64KB total (dbuf)
  __shared__ __bf16 Bs[2][32][64];    // 8KB: rows 0-15 gate, 16-31 up

  int tid = threadIdx.x;
  int lane = tid & 63, w = tid >> 6;
  int quad = lane >> 4, rr = lane & 15;
  int rx = rr & 7;
  int lr = lane >> 3, lc = lane & 7;

  // A sources: row = p*32 + w*8 + lr (row&7 == lr), source chunk lc^lr
  const __bf16* asrc[8];
  #pragma unroll
  for (int p = 0; p < 8; p++) {
    int row = p * 32 + w * 8 + lr;
    int tok = pair_tok[base + ((row < M) ? row : 0)];
    asrc[p] = hid_bf + (size_t)tok * HH + (lc ^ lr) * 8;
  }
  // B sources: 32 rows x 16 float4; thread covers f = q*256+tid
  const float* wbase = w13 + (size_t)e * (2 * II) * HH;
  const float* bsrc[2];
  int boff[2];
  #pragma unroll
  for (int q = 0; q < 2; q++) {
    int f = q * 256 + tid;
    int row = f >> 4, c4 = f & 15;
    int wrow = (row < 16) ? (n0 + row) : (II + n0 + row - 16);
    bsrc[q] = wbase + (size_t)wrow * HH + c4 * 4;
    boff[q] = row * 128 + (((c4 >> 1) ^ (row & 7)) << 4) + (c4 & 1) * 8;
  }

  // prologue: stage tile 0
  #pragma unroll
  for (int p = 0; p < 8; p++) glds16(asrc[p], &As[0][p * 32 + w * 8][0]);
  #pragma unroll
  for (int q = 0; q < 2; q++) st_bf4((char*)&Bs[0][0][0] + boff[q], *(const float4*)(bsrc[q]));
  __syncthreads();

  f32x4 accg[4] = {};
  f32x4 accu[4] = {};
  int cur = 0;

  for (int t = 0; t < HH / 64; t++) {
    int nxt = cur ^ 1;
    bool pf = (t + 1 < HH / 64);
    float4 brA, brB;
    if (pf) {                               // async-stage t+1 (flies under MFMA)
      int k0n = (t + 1) * 64;
      #pragma unroll
      for (int p = 0; p < 8; p++) glds16(asrc[p] + k0n, &As[nxt][p * 32 + w * 8][0]);
      brA = *(const float4*)(bsrc[0] + k0n);
      brB = *(const float4*)(bsrc[1] + k0n);
    }
    const char* ac = (const char*)&As[cur][0][0];
    const char* bc = (const char*)&Bs[cur][0][0];
    #pragma unroll
    for (int ks = 0; ks < 2; ks++) {
      int cx = ((ks * 4 + quad) ^ rx) << 4;
      bf16x8 av[4], bg, bu;
      #pragma unroll
      for (int i = 0; i < 4; i++)
        av[i] = *(const bf16x8*)(ac + (w * 64 + i * 16 + rr) * 128 + cx);
      bg = *(const bf16x8*)(bc + rr * 128 + cx);
      bu = *(const bf16x8*)(bc + (16 + rr) * 128 + cx);
      #pragma unroll
      for (int i = 0; i < 4; i++) {
        accg[i] = __builtin_amdgcn_mfma_f32_16x16x32_bf16(av[i], bg, accg[i], 0, 0, 0);
        accu[i] = __builtin_amdgcn_mfma_f32_16x16x32_bf16(av[i], bu, accu[i], 0, 0, 0);
      }
    }
    if (pf) {                               // B write-late into the other buffer
      st_bf4((char*)&Bs[nxt][0][0] + boff[0], brA);
      st_bf4((char*)&Bs[nxt][0][0] + boff[1], brB);
    }
    __syncthreads();
    cur ^= 1;
  }

  #pragma unroll
  for (int i = 0; i < 4; i++)
    #pragma unroll
    for (int l = 0; l < 4; l++) {
      int m = w * 64 + i * 16 + quad * 4 + l;
      if (m < M) {
        float g = accg[i][l], u = accu[i][l];
        float hv = g / (1.f + expf(-g)) * u;
        h_buf[(size_t)(base + m) * II + n0 + rr] = (__bf16)hv;
      }
    }
}

// ---------------- K4: out[t] += w_p * (h @ w2[e]^T), M=256 x N=32 tile ------
// Same async 2-phase structure; A rows contiguous in h_buf.
__global__ __launch_bounds__(256) void k_w2(const __bf16* __restrict__ h_buf,
                                            const float* __restrict__ w2,
                                            const int* __restrict__ cnt,
                                            const int* __restrict__ offs,
                                            const int* __restrict__ pair_tok,
                                            const float* __restrict__ pair_w,
                                            const int* __restrict__ wl_e,
                                            const int* __restrict__ wl_m0,
                                            const int* __restrict__ nwork,
                                            float* __restrict__ out) {
  int bx = blockIdx.x;
  if (bx >= *nwork) return;
  int e = wl_e[bx], m0w = wl_m0[bx];
  int M = cnt[e] - m0w; if (M > 256) M = 256;
  int base = offs[e] + m0w;
  int h0 = blockIdx.y * 32;

  __shared__ __bf16 As[2][256][64];   // 64KB
  __shared__ __bf16 Bs[2][32][64];    // 8KB
  __shared__ int tl[256];
  __shared__ float wl[256];

  int tid = threadIdx.x;
  int lane = tid & 63, w = tid >> 6;
  int quad = lane >> 4, rr = lane & 15;
  int rx = rr & 7;
  int lr = lane >> 3, lc = lane & 7;

  {
    int ok = tid < M;
    tl[tid] = ok ? pair_tok[base + tid] : 0;
    wl[tid] = ok ? pair_w[base + tid] : 0.f;
  }

  // A: contiguous h_buf rows (rows >= M read in-bounds junk, masked at write)
  const __bf16* asrc[8];
  #pragma unroll
  for (int p = 0; p < 8; p++) {
    int row = p * 32 + w * 8 + lr;
    asrc[p] = h_buf + (size_t)(base + row) * II + (lc ^ lr) * 8;
  }
  // B: w2 rows h0..h0+31
  const float* w_base = w2 + (size_t)e * HH * II;
  const float* bsrc[2];
  int boff[2];
  #pragma unroll
  for (int q = 0; q < 2; q++) {
    int f = q * 256 + tid;
    int row = f >> 4, c4 = f & 15;
    bsrc[q] = w_base + (size_t)(h0 + row) * II + c4 * 4;
    boff[q] = row * 128 + (((c4 >> 1) ^ (row & 7)) << 4) + (c4 & 1) * 8;
  }

  #pragma unroll
  for (int p = 0; p < 8; p++) glds16(asrc[p], &As[0][p * 32 + w * 8][0]);
  #pragma unroll
  for (int q = 0; q < 2; q++) st_bf4((char*)&Bs[0][0][0] + boff[q], *(const float4*)(bsrc[q]));
  __syncthreads();

  f32x4 acc[4][2] = {};
  int cur = 0;

  for (int t = 0; t < II / 64; t++) {
    int nxt = cur ^ 1;
    bool pf = (t + 1 < II / 64);
    float4 brA, brB;
    if (pf) {
      int k0n = (t + 1) * 64;
      #pragma unroll
      for (int p = 0; p < 8; p++) glds16(asrc[p] + k0n, &As[nxt][p * 32 + w * 8][0]);
      brA = *(const float4*)(bsrc[0] + k0n);
      brB = *(const float4*)(bsrc[1] + k0n);
    }
    const char* ac = (const char*)&As[cur][0][0];
    const char* bc = (const char*)&Bs[cur][0][0];
    #pragma unroll
    for (int ks = 0; ks < 2; ks++) {
      int cx = ((ks * 4 + quad) ^ rx) << 4;
      bf16x8 av[4], b[2];
      #pragma unroll
      for (int i = 0; i < 4; i++)
        av[i] = *(const bf16x8*)(ac + (w * 64 + i * 16 + rr) * 128 + cx);
      #pragma unroll
      for (int j = 0; j < 2; j++)
        b[j] = *(const bf16x8*)(bc + (j * 16 + rr) * 128 + cx);
      #pragma unroll
      for (int i = 0; i < 4; i++)
        #pragma unroll
        for (int j = 0; j < 2; j++)
          acc[i][j] = __builtin_amdgcn_mfma_f32_16x16x32_bf16(av[i], b[j], acc[i][j], 0, 0, 0);
    }
    if (pf) {
      st_bf4((char*)&Bs[nxt][0][0] + boff[0], brA);
      st_bf4((char*)&Bs[nxt][0][0] + boff[1], brB);
    }
    __syncthreads();
    cur ^= 1;
  }

  #pragma unroll
  for (int i = 0; i < 4; i++)
    #pragma unroll
    for (int l = 0; l < 4; l++) {
      int m = w * 64 + i * 16 + quad * 4 + l;
      if (m < M) {
        int t = tl[m];
        float wp = wl[m];
        #pragma unroll
        for (int j = 0; j < 2; j++)
          atomicAdd(&out[(size_t)t * HH + h0 + j * 16 + rr], acc[i][j][l] * wp);
      }
    }
}

extern "C" void kernel_launch(void* const* d_in, const int* in_sizes, int n_in,
                              void* d_out, int out_size, void* d_ws, size_t ws_size,
                              hipStream_t stream) {
  const float* hidden = (const float*)d_in[0];
  const float* rw     = (const float*)d_in[1];
  const float* bias   = (const float*)d_in[2];
  const float* w13    = (const float*)d_in[3];
  const float* w2     = (const float*)d_in[4];
  float* out = (float*)d_out;

  int* ws_i = (int*)d_ws;
  int* tok4_id = ws_i;                                    // TT*4
  float* tok4_w = (float*)(tok4_id + TT * TOPK);          // TT*4
  int* pair_tok = (int*)(tok4_w + TT * TOPK);             // TT*4
  float* pair_w = (float*)(pair_tok + TT * TOPK);         // TT*4
  int* cnt = (int*)(pair_w + TT * TOPK);                  // 32
  int* offs = cnt + 32;                                   // 32
  int* wl_e = offs + 32;                                  // 64
  int* wl_m0 = wl_e + 64;                                 // 64
  int* nwork = wl_m0 + 64;                                // 64-int region
  int* gcur = nwork + 16;                                 // 32 (inside region)
  __bf16* hid_bf = (__bf16*)(nwork + 64);                 // TT*HH
  __bf16* h_buf = hid_bf + (size_t)TT * HH;               // (TT*4+256)*II

  k_zero<<<dim3(1), dim3(64), 0, stream>>>(cnt);
  k_router<<<dim3(TT / 4), dim3(256), 0, stream>>>(hidden, rw, bias, out,
                                                   tok4_id, tok4_w, hid_bf, cnt);
  k_scan<<<dim3(1), dim3(64), 0, stream>>>(cnt, offs, wl_e, wl_m0, nwork, gcur);
  k_scatter<<<dim3(32), dim3(256), 0, stream>>>(tok4_id, tok4_w, gcur, pair_tok, pair_w);
  k_w13<<<dim3(MAXW, 32), dim3(256), 0, stream>>>(hid_bf, w13, cnt, offs, pair_tok,
                                                  wl_e, wl_m0, nwork, h_buf);
  k_w2<<<dim3(MAXW, 32), dim3(256), 0, stream>>>(h_buf, w2, cnt, offs, pair_tok, pair_w,
                                                 wl_e, wl_m0, nwork, out);
}

// Round 4
// 386.100 us; speedup vs baseline: 1.1506x; 1.1506x over previous
//
#include <hip/hip_runtime.h>
#include <math.h>

#define TT 2048
#define HH 1024
#define NE 40
#define ER 32
#define II 512
#define TOPK 4
#define RSCALE 2.5f
#define MAXW 64    // max m-tiles of 256: 8192/256 + 32

typedef __bf16 bf16x8 __attribute__((ext_vector_type(8)));
typedef float f32x4 __attribute__((ext_vector_type(4)));

// async global->LDS, 16B per lane; LDS dest is wave-uniform base + lane*16
__device__ __forceinline__ void glds16(const void* g, void* l) {
  __builtin_amdgcn_global_load_lds(
      (const __attribute__((address_space(1))) unsigned int*)g,
      (__attribute__((address_space(3))) unsigned int*)l, 16, 0, 0);
}

__device__ __forceinline__ void st_bf4(void* dst, float4 v) {
  union { __bf16 h[4]; uint2 u; } pk;
  pk.h[0] = (__bf16)v.x; pk.h[1] = (__bf16)v.y;
  pk.h[2] = (__bf16)v.z; pk.h[3] = (__bf16)v.w;
  *(uint2*)dst = pk.u;
}

// ---------------- K0: zero the global expert counters -----------------------
__global__ __launch_bounds__(64) void k_zero(int* __restrict__ cnt) {
  if (threadIdx.x < 32) cnt[threadIdx.x] = 0;
}

// ---------------- K1: fused router (latency-fixed) --------------------------
// Round-3 diagnosis: the old router ran 40 SERIALIZED 6-step shuffle trees
// per token (~8000 cyc dependent latency) — it was the hidden ~190us.
// New structure: per-lane partial dots for ALL 40 experts first (independent
// FMAs), ONE batched butterfly (6x40 pipelined shfls), then fully per-lane
// redundant softmax/top-4 (zero cross-lane dependent chains; all arrays
// statically indexed via full unroll). fp32 logits preserved bit-for-bit
// per-chunk; only the final reduce order matches the old butterfly.
__global__ __launch_bounds__(256) void k_router(const float* __restrict__ hidden,
                                                const float* __restrict__ rw,
                                                const float* __restrict__ bias,
                                                float* __restrict__ out,
                                                int* __restrict__ tok4_id,
                                                float* __restrict__ tok4_w,
                                                __bf16* __restrict__ hid_bf,
                                                int* __restrict__ cnt) {
  int lane = threadIdx.x & 63;
  int t = blockIdx.x * 4 + (threadIdx.x >> 6);
  const float* hrow = hidden + (size_t)t * HH;
  float4 hv[4];
  #pragma unroll
  for (int c = 0; c < 4; c++) hv[c] = *(const float4*)(hrow + c * 256 + lane * 4);

  float acc[NE];
  #pragma unroll
  for (int e = 0; e < NE; e++) {
    const float* wrow = rw + (size_t)e * HH;
    float p = 0.f;
    #pragma unroll
    for (int c = 0; c < 4; c++) {
      float4 w4 = *(const float4*)(wrow + c * 256 + lane * 4);
      p += hv[c].x * w4.x + hv[c].y * w4.y + hv[c].z * w4.z + hv[c].w * w4.w;
    }
    acc[e] = p;
  }
  // batched butterfly: 6 rounds x 40 independent adds, fully pipelined
  #pragma unroll
  for (int off = 32; off; off >>= 1)
    #pragma unroll
    for (int e = 0; e < NE; e++) acc[e] += __shfl_xor(acc[e], off);

  // every lane now holds all 40 logits -> per-lane uniform softmax/top-4
  float m = acc[0];
  #pragma unroll
  for (int e = 1; e < NE; e++) m = fmaxf(m, acc[e]);
  float s = 0.f;
  #pragma unroll
  for (int e = 0; e < NE; e++) { acc[e] = expf(acc[e] - m); s += acc[e]; }
  float inv = 1.f / s;
  float v[NE];
  #pragma unroll
  for (int e = 0; e < NE; e++) { acc[e] *= inv; v[e] = acc[e] + bias[e]; }

  int ids[TOPK]; float wv[TOPK];
  #pragma unroll
  for (int k = 0; k < TOPK; k++) {
    float mv = -INFINITY, mw = 0.f; int mi = 0;
    #pragma unroll
    for (int e = 0; e < NE; e++)
      if (v[e] > mv) { mv = v[e]; mi = e; mw = acc[e]; }   // strict > : tie -> lower idx
    ids[k] = mi;
    wv[k] = RSCALE * mw;                                   // weight from UNBIASED score
    #pragma unroll
    for (int e = 0; e < NE; e++) if (e == mi) v[e] = -INFINITY;  // static idx (rule 20)
  }
  float zt = 0.f;
  #pragma unroll
  for (int k = 0; k < TOPK; k++) if (ids[k] >= ER) zt += wv[k];
  if (lane == 0) {
    #pragma unroll
    for (int k = 0; k < TOPK; k++) {
      tok4_id[t * TOPK + k] = ids[k];
      tok4_w[t * TOPK + k] = wv[k];
      if (ids[k] < ER) atomicAdd(&cnt[ids[k]], 1);
    }
  }
  #pragma unroll
  for (int c = 0; c < 4; c++) {
    int j = c * 256 + lane * 4;
    float4 h4 = hv[c];
    *(float4*)(out + (size_t)t * HH + j) =
        make_float4(h4.x * zt, h4.y * zt, h4.z * zt, h4.w * zt);
    union { __bf16 h[4]; uint2 u; } pk;
    pk.h[0] = (__bf16)h4.x; pk.h[1] = (__bf16)h4.y;
    pk.h[2] = (__bf16)h4.z; pk.h[3] = (__bf16)h4.w;
    *(uint2*)(hid_bf + (size_t)t * HH + j) = pk.u;
  }
}

// ---------------- K2a: tiny scan over 32 counters + worklist ----------------
__global__ __launch_bounds__(64) void k_scan(const int* __restrict__ cnt,
                                             int* __restrict__ offs,
                                             int* __restrict__ wl_e,
                                             int* __restrict__ wl_m0,
                                             int* __restrict__ nwork,
                                             int* __restrict__ gcur) {
  int lane = threadIdx.x;
  int c = (lane < ER) ? cnt[lane] : 0;
  int ts = (c + 255) >> 8;                  // 256-row tiles
  int ps = c, pt = ts;
  #pragma unroll
  for (int off = 1; off < 32; off <<= 1) {
    int v1 = __shfl_up(ps, off);
    int v2 = __shfl_up(pt, off);
    if (lane >= off) { ps += v1; pt += v2; }
  }
  if (lane < ER) {
    int o = ps - c;
    offs[lane] = o; gcur[lane] = o;
    int tb = pt - ts;
    for (int i = 0; i < ts; i++) { wl_e[tb + i] = lane; wl_m0[tb + i] = i * 256; }
  }
  if (lane == 31) *nwork = pt;
}

// ---------------- K2b: parallel scatter (32 blocks, global-atomic slots) ----
__global__ __launch_bounds__(256) void k_scatter(const int* __restrict__ tok4_id,
                                                 const float* __restrict__ tok4_w,
                                                 int* __restrict__ gcur,
                                                 int* __restrict__ pair_tok,
                                                 float* __restrict__ pair_w) {
  int idx = blockIdx.x * 256 + threadIdx.x;
  int id = tok4_id[idx];
  if (id < ER) {
    int pos = atomicAdd(&gcur[id], 1);
    pair_tok[pos] = idx >> 2;
    pair_w[pos] = tok4_w[idx];
  }
}

// ---------------- K3: h = silu(X@Wg^T)*(X@Wu^T), M=256 x 32 cols ------------
// r0 geometry (B=64 rows, grid y=16) + counted-vmcnt schedule (T3/T4):
// raw s_barrier + s_waitcnt vmcnt(12) — tile t+1's 12 loads stay in flight
// across the barrier and under tile t's MFMAs (never drain to 0 mid-loop).
// B (fp32 weights, HBM) prefetched 2 tiles deep into static reg banks
// br0/br1 (2x-unrolled loop body -> compile-time bank); A (L2-hot) 1 deep
// via glds. Swizzle: pre-swizzled global source + linear glds dest + XOR'd
// read (rule 21). LDS 80KB.
__global__ __launch_bounds__(256) void k_w13(const __bf16* __restrict__ hid_bf,
                                             const float* __restrict__ w13,
                                             const int* __restrict__ cnt,
                                             const int* __restrict__ offs,
                                             const int* __restrict__ pair_tok,
                                             const int* __restrict__ wl_e,
                                             const int* __restrict__ wl_m0,
                                             const int* __restrict__ nwork,
                                             __bf16* __restrict__ h_buf) {
  int bx = blockIdx.x;
  if (bx >= *nwork) return;
  int e = wl_e[bx], m0w = wl_m0[bx];
  int M = cnt[e] - m0w; if (M > 256) M = 256;
  int base = offs[e] + m0w;
  int n0 = blockIdx.y * 32;

  __shared__ __bf16 As[2][256][64];   // 64KB
  __shared__ __bf16 Bs[2][64][64];    // 16KB: rows 0-31 gate, 32-63 up

  int tid = threadIdx.x;
  int lane = tid & 63, w = tid >> 6;
  int quad = lane >> 4, rr = lane & 15;
  int rx = rr & 7;
  int lr = lane >> 3, lc = lane & 7;

  // A sources: row = p*32 + w*8 + lr, pre-swizzled source chunk lc^lr
  const __bf16* asrc[8];
  #pragma unroll
  for (int p = 0; p < 8; p++) {
    int row = p * 32 + w * 8 + lr;
    int tok = pair_tok[base + ((row < M) ? row : 0)];
    asrc[p] = hid_bf + (size_t)tok * HH + (lc ^ lr) * 8;
  }
  // B sources: 64 rows x 16 float4 -> 4 per thread
  const float* wbase = w13 + (size_t)e * (2 * II) * HH;
  const float* bsrc[4];
  int boff[4];
  #pragma unroll
  for (int q = 0; q < 4; q++) {
    int f = q * 256 + tid;
    int row = f >> 4, c4 = f & 15;
    int wrow = (row < 32) ? (n0 + row) : (II + n0 + row - 32);
    bsrc[q] = wbase + (size_t)wrow * HH + c4 * 4;
    boff[q] = row * 128 + (((c4 >> 1) ^ (row & 7)) << 4) + (c4 & 1) * 8;
  }

  f32x4 accg[4][2] = {};
  f32x4 accu[4][2] = {};
  float4 br0[4], br1[4];

  // prologue: B(0)->br0, B(1)->br1, glds A(0), ds_write B(0)
  #pragma unroll
  for (int q = 0; q < 4; q++) br0[q] = *(const float4*)(bsrc[q]);
  #pragma unroll
  for (int q = 0; q < 4; q++) br1[q] = *(const float4*)(bsrc[q] + 64);
  #pragma unroll
  for (int p = 0; p < 8; p++) glds16(asrc[p], &As[0][p * 32 + w * 8][0]);
  {
    char* b0 = (char*)&Bs[0][0][0];
    #pragma unroll
    for (int q = 0; q < 4; q++) st_bf4(b0 + boff[q], br0[q]);
  }
  asm volatile("s_waitcnt lgkmcnt(0)" ::: "memory");

#define BODY13(T, BRLD, BRST)                                                     \
  {                                                                               \
    const int tI = (T);                                                           \
    if (tI + 2 < 16) {                                                            \
      int kk = (tI + 2) * 64;                                                     \
      _Pragma("unroll") for (int q = 0; q < 4; q++)                               \
          BRLD[q] = *(const float4*)(bsrc[q] + kk);                               \
    }                                                                             \
    if (tI + 1 < 16) {                                                            \
      int kk = (tI + 1) * 64;                                                     \
      _Pragma("unroll") for (int p = 0; p < 8; p++)                               \
          glds16(asrc[p] + kk, &As[(tI + 1) & 1][p * 32 + w * 8][0]);             \
      asm volatile("s_waitcnt vmcnt(12)" ::: "memory");                           \
    } else {                                                                      \
      asm volatile("s_waitcnt vmcnt(0)" ::: "memory");                            \
    }                                                                             \
    __builtin_amdgcn_sched_barrier(0);                                            \
    __builtin_amdgcn_s_barrier();                                                 \
    __builtin_amdgcn_sched_barrier(0);                                            \
    const char* ac = (const char*)&As[tI & 1][0][0];                              \
    const char* bc = (const char*)&Bs[tI & 1][0][0];                              \
    _Pragma("unroll") for (int ks = 0; ks < 2; ks++) {                            \
      int cx = ((ks * 4 + quad) ^ rx) << 4;                                       \
      bf16x8 av[4], bg[2], bu[2];                                                 \
      _Pragma("unroll") for (int i = 0; i < 4; i++)                               \
          av[i] = *(const bf16x8*)(ac + (w * 64 + i * 16 + rr) * 128 + cx);       \
      _Pragma("unroll") for (int j = 0; j < 2; j++) {                             \
        bg[j] = *(const bf16x8*)(bc + (j * 16 + rr) * 128 + cx);                  \
        bu[j] = *(const bf16x8*)(bc + (32 + j * 16 + rr) * 128 + cx);             \
      }                                                                           \
      _Pragma("unroll") for (int i = 0; i < 4; i++)                               \
          _Pragma("unroll") for (int j = 0; j < 2; j++) {                         \
        accg[i][j] = __builtin_amdgcn_mfma_f32_16x16x32_bf16(av[i], bg[j],        \
                                                             accg[i][j], 0, 0, 0);\
        accu[i][j] = __builtin_amdgcn_mfma_f32_16x16x32_bf16(av[i], bu[j],        \
                                                             accu[i][j], 0, 0, 0);\
      }                                                                           \
    }                                                                             \
    if (tI + 1 < 16) {                                                            \
      char* bn = (char*)&Bs[(tI + 1) & 1][0][0];                                  \
      _Pragma("unroll") for (int q = 0; q < 4; q++) st_bf4(bn + boff[q], BRST[q]);\
    }                                                                             \
    asm volatile("s_waitcnt lgkmcnt(0)" ::: "memory");                            \
    __builtin_amdgcn_sched_barrier(0);                                            \
    __builtin_amdgcn_s_barrier();                                                 \
  }

  for (int t = 0; t < 16; t += 2) {
    BODY13(t, br0, br1);       // even: load B(t+2)->bank0, write B(t+1) from bank1
    BODY13(t + 1, br1, br0);   // odd:  load B(t+3)->bank1, write B(t+2) from bank0
  }
#undef BODY13

  #pragma unroll
  for (int i = 0; i < 4; i++)
    #pragma unroll
    for (int j = 0; j < 2; j++)
      #pragma unroll
      for (int l = 0; l < 4; l++) {
        int m = w * 64 + i * 16 + quad * 4 + l;
        if (m < M) {
          float g = accg[i][j][l], u = accu[i][j][l];
          float hv = g / (1.f + expf(-g)) * u;
          h_buf[(size_t)(base + m) * II + n0 + j * 16 + rr] = (__bf16)hv;
        }
      }
}

// ---------------- K4: out[t] += w_p * (h @ w2[e]^T), M=256 x N=64 -----------
// Same counted-vmcnt schedule; r0 geometry (N=64, grid y=16, 8 K-iters).
__global__ __launch_bounds__(256) void k_w2(const __bf16* __restrict__ h_buf,
                                            const float* __restrict__ w2,
                                            const int* __restrict__ cnt,
                                            const int* __restrict__ offs,
                                            const int* __restrict__ pair_tok,
                                            const float* __restrict__ pair_w,
                                            const int* __restrict__ wl_e,
                                            const int* __restrict__ wl_m0,
                                            const int* __restrict__ nwork,
                                            float* __restrict__ out) {
  int bx = blockIdx.x;
  if (bx >= *nwork) return;
  int e = wl_e[bx], m0w = wl_m0[bx];
  int M = cnt[e] - m0w; if (M > 256) M = 256;
  int base = offs[e] + m0w;
  int h0 = blockIdx.y * 64;

  __shared__ __bf16 As[2][256][64];   // 64KB
  __shared__ __bf16 Bs[2][64][64];    // 16KB
  __shared__ int tl[256];
  __shared__ float wl[256];

  int tid = threadIdx.x;
  int lane = tid & 63, w = tid >> 6;
  int quad = lane >> 4, rr = lane & 15;
  int rx = rr & 7;
  int lr = lane >> 3, lc = lane & 7;

  {
    int ok = tid < M;
    tl[tid] = ok ? pair_tok[base + tid] : 0;
    wl[tid] = ok ? pair_w[base + tid] : 0.f;
  }

  // A: contiguous h_buf rows (rows >= M read 0xAA junk ~1e-13, masked at write)
  const __bf16* asrc[8];
  #pragma unroll
  for (int p = 0; p < 8; p++) {
    int row = p * 32 + w * 8 + lr;
    asrc[p] = h_buf + (size_t)(base + row) * II + (lc ^ lr) * 8;
  }
  // B: w2 rows h0..h0+63, 4 float4 per thread
  const float* w_base = w2 + (size_t)e * HH * II;
  const float* bsrc[4];
  int boff[4];
  #pragma unroll
  for (int q = 0; q < 4; q++) {
    int f = q * 256 + tid;
    int row = f >> 4, c4 = f & 15;
    bsrc[q] = w_base + (size_t)(h0 + row) * II + c4 * 4;
    boff[q] = row * 128 + (((c4 >> 1) ^ (row & 7)) << 4) + (c4 & 1) * 8;
  }

  f32x4 acc[4][4] = {};
  float4 br0[4], br1[4];

  #pragma unroll
  for (int q = 0; q < 4; q++) br0[q] = *(const float4*)(bsrc[q]);
  #pragma unroll
  for (int q = 0; q < 4; q++) br1[q] = *(const float4*)(bsrc[q] + 64);
  #pragma unroll
  for (int p = 0; p < 8; p++) glds16(asrc[p], &As[0][p * 32 + w * 8][0]);
  {
    char* b0 = (char*)&Bs[0][0][0];
    #pragma unroll
    for (int q = 0; q < 4; q++) st_bf4(b0 + boff[q], br0[q]);
  }
  asm volatile("s_waitcnt lgkmcnt(0)" ::: "memory");

#define BODY2(T, BRLD, BRST)                                                      \
  {                                                                               \
    const int tI = (T);                                                           \
    if (tI + 2 < 8) {                                                             \
      int kk = (tI + 2) * 64;                                                     \
      _Pragma("unroll") for (int q = 0; q < 4; q++)                               \
          BRLD[q] = *(const float4*)(bsrc[q] + kk);                               \
    }                                                                             \
    if (tI + 1 < 8) {                                                             \
      int kk = (tI + 1) * 64;                                                     \
      _Pragma("unroll") for (int p = 0; p < 8; p++)                               \
          glds16(asrc[p] + kk, &As[(tI + 1) & 1][p * 32 + w * 8][0]);             \
      asm volatile("s_waitcnt vmcnt(12)" ::: "memory");                           \
    } else {                                                                      \
      asm volatile("s_waitcnt vmcnt(0)" ::: "memory");                            \
    }                                                                             \
    __builtin_amdgcn_sched_barrier(0);                                            \
    __builtin_amdgcn_s_barrier();                                                 \
    __builtin_amdgcn_sched_barrier(0);                                            \
    const char* ac = (const char*)&As[tI & 1][0][0];                              \
    const char* bc = (const char*)&Bs[tI & 1][0][0];                              \
    _Pragma("unroll") for (int ks = 0; ks < 2; ks++) {                            \
      int cx = ((ks * 4 + quad) ^ rx) << 4;                                       \
      bf16x8 av[4], b[4];                                                         \
      _Pragma("unroll") for (int i = 0; i < 4; i++)                               \
          av[i] = *(const bf16x8*)(ac + (w * 64 + i * 16 + rr) * 128 + cx);       \
      _Pragma("unroll") for (int j = 0; j < 4; j++)                               \
          b[j] = *(const bf16x8*)(bc + (j * 16 + rr) * 128 + cx);                 \
      _Pragma("unroll") for (int i = 0; i < 4; i++)                               \
          _Pragma("unroll") for (int j = 0; j < 4; j++)                           \
              acc[i][j] = __builtin_amdgcn_mfma_f32_16x16x32_bf16(av[i], b[j],    \
                                                            acc[i][j], 0, 0, 0); \
    }                                                                             \
    if (tI + 1 < 8) {                                                             \
      char* bn = (char*)&Bs[(tI + 1) & 1][0][0];                                  \
      _Pragma("unroll") for (int q = 0; q < 4; q++) st_bf4(bn + boff[q], BRST[q]);\
    }                                                                             \
    asm volatile("s_waitcnt lgkmcnt(0)" ::: "memory");                            \
    __builtin_amdgcn_sched_barrier(0);                                            \
    __builtin_amdgcn_s_barrier();                                                 \
  }

  for (int t = 0; t < 8; t += 2) {
    BODY2(t, br0, br1);
    BODY2(t + 1, br1, br0);
  }
#undef BODY2

  #pragma unroll
  for (int i = 0; i < 4; i++)
    #pragma unroll
    for (int l = 0; l < 4; l++) {
      int m = w * 64 + i * 16 + quad * 4 + l;
      if (m < M) {
        int t = tl[m];
        float wp = wl[m];
        #pragma unroll
        for (int j = 0; j < 4; j++)
          atomicAdd(&out[(size_t)t * HH + h0 + j * 16 + rr], acc[i][j][l] * wp);
      }
    }
}

extern "C" void kernel_launch(void* const* d_in, const int* in_sizes, int n_in,
                              void* d_out, int out_size, void* d_ws, size_t ws_size,
                              hipStream_t stream) {
  const float* hidden = (const float*)d_in[0];
  const float* rw     = (const float*)d_in[1];
  const float* bias   = (const float*)d_in[2];
  const float* w13    = (const float*)d_in[3];
  const float* w2     = (const float*)d_in[4];
  float* out = (float*)d_out;

  int* ws_i = (int*)d_ws;
  int* tok4_id = ws_i;                                    // TT*4
  float* tok4_w = (float*)(tok4_id + TT * TOPK);          // TT*4
  int* pair_tok = (int*)(tok4_w + TT * TOPK);             // TT*4
  float* pair_w = (float*)(pair_tok + TT * TOPK);         // TT*4
  int* cnt = (int*)(pair_w + TT * TOPK);                  // 32
  int* offs = cnt + 32;                                   // 32
  int* wl_e = offs + 32;                                  // 64
  int* wl_m0 = wl_e + 64;                                 // 64
  int* nwork = wl_m0 + 64;                                // 64-int region
  int* gcur = nwork + 16;                                 // 32 (inside region)
  __bf16* hid_bf = (__bf16*)(nwork + 64);                 // TT*HH
  __bf16* h_buf = hid_bf + (size_t)TT * HH;               // (TT*4+256)*II

  k_zero<<<dim3(1), dim3(64), 0, stream>>>(cnt);
  k_router<<<dim3(TT / 4), dim3(256), 0, stream>>>(hidden, rw, bias, out,
                                                   tok4_id, tok4_w, hid_bf, cnt);
  k_scan<<<dim3(1), dim3(64), 0, stream>>>(cnt, offs, wl_e, wl_m0, nwork, gcur);
  k_scatter<<<dim3(32), dim3(256), 0, stream>>>(tok4_id, tok4_w, gcur, pair_tok, pair_w);
  k_w13<<<dim3(MAXW, 16), dim3(256), 0, stream>>>(hid_bf, w13, cnt, offs, pair_tok,
                                                  wl_e, wl_m0, nwork, h_buf);
  k_w2<<<dim3(MAXW, 16), dim3(256), 0, stream>>>(h_buf, w2, cnt, offs, pair_tok, pair_w,
                                                 wl_e, wl_m0, nwork, out);
}